// Round 5
// baseline (321.570 us; speedup 1.0000x reference)
//
#include <hip/hip_runtime.h>
#include <cstdint>

typedef __bf16 bf16x8 __attribute__((ext_vector_type(8)));
typedef float f32x16 __attribute__((ext_vector_type(16)));

__device__ __forceinline__ unsigned short f2b(float f) {
    union { float f; uint32_t u; } x; x.f = f;
    uint32_t r = (x.u + 0x7fffu + ((x.u >> 16) & 1u)) >> 16;
    return (unsigned short)r;
}
__device__ __forceinline__ float b2f(unsigned short h) {
    union { float f; uint32_t u; } x; x.u = ((uint32_t)h) << 16;
    return x.f;
}

// Fragment-linear layout F(M,K) (identical for A and B operands of
// v_mfma_f32_32x32x16_bf16; lane mapping m=lane&31, k=(lane>>5)*8+j):
// element (m,k) at ((m>>5)*(K>>4) + (k>>4))*512 + (((k>>3)&1)*32 + (m&31))*8 + (k&7).
// A wave's fragment for (mblk,kstep) is one coalesced 1KB run: base + lane*8.
__device__ __forceinline__ long foff(int n, int k, int K) {
    return ((long)(n >> 5) * (K >> 4) + (k >> 4)) * 512 + (((k >> 3) & 1) * 32 + (n & 31)) * 8 + (k & 7);
}

// -------- convert x (fp32) -> Xf frag-linear F(8192, 1024) bf16 --------
__global__ __launch_bounds__(256) void convert_x_kernel(const float* __restrict__ x,
                                                        unsigned short* __restrict__ Xf) {
    int t = blockIdx.x * 256 + threadIdx.x;
    int m = t >> 7;              // row 0..8191
    int k0 = (t & 127) * 8;      // 8 consecutive k
    const float* p = x + (long)m * 1024 + k0;
    float4 v0 = *(const float4*)p;
    float4 v1 = *(const float4*)(p + 4);
    long off = ((long)(m >> 5) * 64 + (k0 >> 4)) * 512 + (((k0 >> 3) & 1) * 32 + (m & 31)) * 8;
    ushort4 o0, o1;
    o0.x = f2b(v0.x); o0.y = f2b(v0.y); o0.z = f2b(v0.z); o0.w = f2b(v0.w);
    o1.x = f2b(v1.x); o1.y = f2b(v1.y); o1.z = f2b(v1.z); o1.w = f2b(v1.w);
    *(ushort4*)(Xf + off) = o0;
    *(ushort4*)(Xf + off + 4) = o1;
}

// ------- transpose+convert W[k][n] -> frag-linear Wf = F(3072, 1024) -------
__global__ __launch_bounds__(1024) void transpose_w_kernel(const float* __restrict__ Wq,
                                                           const float* __restrict__ Wk,
                                                           const float* __restrict__ Wv,
                                                           unsigned short* __restrict__ Wf) {
    __shared__ float tile[32][33];
    const float* W = (blockIdx.z == 0) ? Wq : (blockIdx.z == 1) ? Wk : Wv;
    int n0 = blockIdx.x * 32, k0 = blockIdx.y * 32;
    int tx = threadIdx.x, ty = threadIdx.y;
    tile[ty][tx] = W[(k0 + ty) * 1024 + n0 + tx];
    __syncthreads();
    int n = blockIdx.z * 1024 + n0 + ty;
    int k = k0 + tx;
    Wf[foff(n, k, 1024)] = f2b(tile[tx][ty]);
}

// ------------- pure-flatmm bf16 MFMA GEMM: C[m][n] = sum_k A[m][k]*B[n][k] -------------
// Both operands frag-linear in global. NO LDS, NO barriers: per 32-K iteration,
// 8 coalesced global_load_dwordx4 (next iter's frags) + 8 MFMA on current frags.
// Compiler emits s_waitcnt vmcnt(8)-style waits -- loads stay in flight across
// the whole compute phase (AITER-style 1:1 interleave, vmcnt never 0).
// 128x128 block tile, 4 waves (2x2 of 64x64 wave-tiles, 2x2 32x32 MFMA frags).
// EPI 0: QKV epilogue (bias; Q scaled -> F(2048,1024)/batch; K -> F(2048,1024)/batch;
//        V -> F(1024,2048)/batch)
// EPI 1: bf16 row-major S (ldc 2048)
// EPI 2: fp32 row-major out (ldc 1024)
template <int EPI>
__global__ __launch_bounds__(256) void gemm_ff(const unsigned short* __restrict__ Af, long sA,
                                               const unsigned short* __restrict__ Bf, long sB,
                                               void* __restrict__ Cv, long sC, int K,
                                               const float* __restrict__ bq, const float* __restrict__ bk,
                                               const float* __restrict__ bv,
                                               unsigned short* __restrict__ Qf,
                                               unsigned short* __restrict__ Kf,
                                               unsigned short* __restrict__ Vf) {
    const int tid = threadIdx.x;
    const int wave = tid >> 6, lane = tid & 63;
    const int h = lane >> 5;
    const int l31 = lane & 31;
    const int wm = wave >> 1, wn = wave & 1;
    const long bm = (long)blockIdx.y * 128;
    const long bn = (long)blockIdx.x * 128;
    const int nk = K >> 4;

    const unsigned short* Ab = Af + (long)blockIdx.z * sA;
    const unsigned short* Bb = Bf + (long)blockIdx.z * sB;

    const unsigned short* ap[2];
    const unsigned short* bp[2];
#pragma unroll
    for (int i = 0; i < 2; ++i) {
        ap[i] = Ab + ((bm >> 5) + wm * 2 + i) * (long)nk * 512 + lane * 8;
        bp[i] = Bb + ((bn >> 5) + wn * 2 + i) * (long)nk * 512 + lane * 8;
    }

    f32x16 acc[2][2];
#pragma unroll
    for (int mi = 0; mi < 2; ++mi)
#pragma unroll
        for (int ni = 0; ni < 2; ++ni)
#pragma unroll
            for (int r = 0; r < 16; ++r) acc[mi][ni][r] = 0.0f;

    bf16x8 fa[2][2], fb[2][2];
#pragma unroll
    for (int s = 0; s < 2; ++s)
#pragma unroll
        for (int i = 0; i < 2; ++i) {
            fa[s][i] = *(const bf16x8*)(ap[i] + (long)s * 512);
            fb[s][i] = *(const bf16x8*)(bp[i] + (long)s * 512);
        }

#pragma unroll 2
    for (int ks = 0; ks < nk; ks += 2) {
        const int kp = (ks + 2 < nk) ? (ks + 2) : 0;   // clamp: harmless re-load at tail
        bf16x8 na[2][2], nb[2][2];
#pragma unroll
        for (int s = 0; s < 2; ++s)
#pragma unroll
            for (int i = 0; i < 2; ++i) {
                na[s][i] = *(const bf16x8*)(ap[i] + (long)(kp + s) * 512);
                nb[s][i] = *(const bf16x8*)(bp[i] + (long)(kp + s) * 512);
            }
#pragma unroll
        for (int s = 0; s < 2; ++s)
#pragma unroll
            for (int mi = 0; mi < 2; ++mi)
#pragma unroll
                for (int ni = 0; ni < 2; ++ni)
                    acc[mi][ni] = __builtin_amdgcn_mfma_f32_32x32x16_bf16(fa[s][mi], fb[s][ni],
                                                                          acc[mi][ni], 0, 0, 0);
#pragma unroll
        for (int s = 0; s < 2; ++s)
#pragma unroll
            for (int i = 0; i < 2; ++i) { fa[s][i] = na[s][i]; fb[s][i] = nb[s][i]; }
    }

    // ---- epilogue. 32x32 C/D layout: col = lane&31, row = (reg&3) + 8*(reg>>2) + 4*(lane>>5)
#pragma unroll
    for (int mi = 0; mi < 2; ++mi) {
#pragma unroll
        for (int ni = 0; ni < 2; ++ni) {
            const f32x16 a = acc[mi][ni];
            const long col = bn + wn * 64 + ni * 32 + l31;
            const long rowB = bm + wm * 64 + mi * 32 + h * 4;
            if constexpr (EPI == 0) {
                const long batch = rowB >> 11;
                const int tokB = (int)(rowB & 2047) & ~31;     // 32-aligned token block
                if (col < 2048) {
                    // Q or K -> F(2048 tokens, 1024 e) per batch
                    const bool isQ = (col < 1024);
                    const int e = (int)(isQ ? col : col - 1024);
                    const float bias = isQ ? bq[e] : bk[e];
                    const float scl = isQ ? 0.03125f : 1.0f;
                    unsigned short* outb = isQ ? Qf : Kf;
                    unsigned short* dst = outb + batch * (2048L * 1024) +
                                          ((long)(tokB >> 5) * 64 + (e >> 4)) * 512 +
                                          (long)(((e >> 3) & 1) * 32) * 8 + (e & 7);
#pragma unroll
                    for (int g = 0; g < 4; ++g)
#pragma unroll
                        for (int r = 0; r < 4; ++r) {
                            const int tok31 = (int)((rowB + g * 8 + r) & 31);
                            dst[tok31 * 8] = f2b((a[g * 4 + r] + bias) * scl);
                        }
                } else {
                    // V -> F(1024 e, 2048 tokens) per batch
                    const int e = (int)col - 2048;
                    const float bias = bv[e];
                    unsigned short* base = Vf + batch * (2048L * 1024) + (long)(e >> 5) * 128 * 512 + l31 * 8;
#pragma unroll
                    for (int g = 0; g < 4; ++g)
#pragma unroll
                        for (int r = 0; r < 4; ++r) {
                            const int tok = (int)((rowB + g * 8 + r) & 2047);
                            base[((long)(tok >> 4)) * 512 + (long)(((tok >> 3) & 1) * 32) * 8 + (tok & 7)] =
                                f2b(a[g * 4 + r] + bias);
                        }
                }
            } else if constexpr (EPI == 1) {
                unsigned short* S = (unsigned short*)Cv + (long)blockIdx.z * sC;
#pragma unroll
                for (int g = 0; g < 4; ++g)
#pragma unroll
                    for (int r = 0; r < 4; ++r)
                        S[(rowB + g * 8 + r) * 2048 + col] = f2b(a[g * 4 + r]);
            } else {
                float* O = (float*)Cv + (long)blockIdx.z * sC;
#pragma unroll
                for (int g = 0; g < 4; ++g)
#pragma unroll
                    for (int r = 0; r < 4; ++r)
                        O[(rowB + g * 8 + r) * 1024 + col] = a[g * 4 + r];
            }
        }
    }
}

// ------- row softmax over 2048 bf16; read row-major S, write frag-linear Pf -------
__global__ __launch_bounds__(256) void softmax_kernel(const unsigned short* __restrict__ S,
                                                      unsigned short* __restrict__ Pf) {
    const long row = blockIdx.x;                 // global row 0..8191
    const unsigned short* p = S + row * 2048;
    const int tid = threadIdx.x;
    const int wave = tid >> 6, lane = tid & 63;

    ushort4 u0 = *(const ushort4*)&p[tid * 8];
    ushort4 u1 = *(const ushort4*)&p[tid * 8 + 4];
    float v[8];
    v[0] = b2f(u0.x); v[1] = b2f(u0.y); v[2] = b2f(u0.z); v[3] = b2f(u0.w);
    v[4] = b2f(u1.x); v[5] = b2f(u1.y); v[6] = b2f(u1.z); v[7] = b2f(u1.w);

    float m = v[0];
#pragma unroll
    for (int j = 1; j < 8; ++j) m = fmaxf(m, v[j]);
#pragma unroll
    for (int off = 32; off; off >>= 1) m = fmaxf(m, __shfl_xor(m, off, 64));
    __shared__ float redm[4];
    __shared__ float reds[4];
    if (lane == 0) redm[wave] = m;
    __syncthreads();
    m = fmaxf(fmaxf(redm[0], redm[1]), fmaxf(redm[2], redm[3]));

    float s = 0.0f;
#pragma unroll
    for (int j = 0; j < 8; ++j) { v[j] = __expf(v[j] - m); s += v[j]; }
#pragma unroll
    for (int off = 32; off; off >>= 1) s += __shfl_xor(s, off, 64);
    if (lane == 0) reds[wave] = s;
    __syncthreads();
    s = reds[0] + reds[1] + reds[2] + reds[3];
    const float inv = 1.0f / s;

    u0.x = f2b(v[0] * inv); u0.y = f2b(v[1] * inv); u0.z = f2b(v[2] * inv); u0.w = f2b(v[3] * inv);
    u1.x = f2b(v[4] * inv); u1.y = f2b(v[5] * inv); u1.z = f2b(v[6] * inv); u1.w = f2b(v[7] * inv);

    // write frag-linear: batch = row>>11, r2 = row&2047, k0 = tid*8 (K=2048)
    const long batch = row >> 11;
    const int r2 = (int)(row & 2047);
    unsigned short* q = Pf + batch * (2048L * 2048) +
                        ((long)(r2 >> 5) * 128 + (tid >> 1)) * 512 + ((tid & 1) * 32 + (r2 & 31)) * 8;
    *(ushort4*)q = u0;
    *(ushort4*)(q + 4) = u1;
}

extern "C" void kernel_launch(void* const* d_in, const int* in_sizes, int n_in,
                              void* d_out, int out_size, void* d_ws, size_t ws_size,
                              hipStream_t stream) {
    const float* x  = (const float*)d_in[0];
    const float* Wq = (const float*)d_in[1];
    const float* Wk = (const float*)d_in[2];
    const float* Wv = (const float*)d_in[3];
    const float* bq = (const float*)d_in[4];
    const float* bk = (const float*)d_in[5];
    const float* bv = (const float*)d_in[6];
    float* out = (float*)d_out;

    char* ws = (char*)d_ws;
    unsigned short* Xf = (unsigned short*)ws; ws += 8192L * 1024 * 2;   // F(8192,1024)
    unsigned short* Wf = (unsigned short*)ws; ws += 3072L * 1024 * 2;   // F(3072,1024)
    unsigned short* Qf = (unsigned short*)ws; ws += 8192L * 1024 * 2;   // F(2048,1024) x4
    unsigned short* Kf = (unsigned short*)ws; ws += 8192L * 1024 * 2;   // F(2048,1024) x4
    unsigned short* Vf = (unsigned short*)ws; ws += 8192L * 1024 * 2;   // F(1024,2048) x4
    unsigned short* S  = (unsigned short*)ws; ws += 4L * 2048 * 2048 * 2;  // row-major
    unsigned short* Pf = (unsigned short*)ws; ws += 4L * 2048 * 2048 * 2;  // F(2048,2048) x4

    convert_x_kernel<<<4096, 256, 0, stream>>>(x, Xf);
    transpose_w_kernel<<<dim3(32, 32, 3), dim3(32, 32), 0, stream>>>(Wq, Wk, Wv, Wf);
    // QKV projection: [8192,3072] = Xf @ Wf^T (+bias; Q scaled; Q,K,V frag-packed)
    gemm_ff<0><<<dim3(24, 64, 1), 256, 0, stream>>>(Xf, 0, Wf, 0,
                                                    nullptr, 0, 1024, bq, bk, bv, Qf, Kf, Vf);
    // S[b] = Q[b] @ K[b]^T (Q pre-scaled by 1/32), row-major bf16
    gemm_ff<1><<<dim3(16, 16, 4), 256, 0, stream>>>(Qf, 2048L * 1024, Kf, 2048L * 1024,
                                                    S, 2048L * 2048, 1024,
                                                    nullptr, nullptr, nullptr, nullptr, nullptr, nullptr);
    // softmax rows; emit P frag-linear
    softmax_kernel<<<8192, 256, 0, stream>>>(S, Pf);
    // out[b] = P[b] @ V[b] (fp32 out)
    gemm_ff<2><<<dim3(8, 16, 4), 256, 0, stream>>>(Pf, 2048L * 2048, Vf, 2048L * 1024,
                                                   out, 2048L * 1024, 2048,
                                                   nullptr, nullptr, nullptr, nullptr, nullptr, nullptr);
}

// Round 6
// 292.146 us; speedup vs baseline: 1.1007x; 1.1007x over previous
//
#include <hip/hip_runtime.h>
#include <cstdint>

typedef __bf16 bf16x8 __attribute__((ext_vector_type(8)));
typedef float f32x16 __attribute__((ext_vector_type(16)));

__device__ __forceinline__ unsigned short f2b(float f) {
    union { float f; uint32_t u; } x; x.f = f;
    uint32_t r = (x.u + 0x7fffu + ((x.u >> 16) & 1u)) >> 16;
    return (unsigned short)r;
}
__device__ __forceinline__ float b2f(unsigned short h) {
    union { float f; uint32_t u; } x; x.u = ((uint32_t)h) << 16;
    return x.f;
}

// ---------------- convert x (fp32 -> bf16), row-major ----------------
__global__ __launch_bounds__(256) void convert_x_kernel(const float* __restrict__ x,
                                                        unsigned short* __restrict__ xb) {
    int i = (blockIdx.x * 256 + threadIdx.x) * 4;
    float4 v = *(const float4*)(x + i);
    ushort4 o;
    o.x = f2b(v.x); o.y = f2b(v.y); o.z = f2b(v.z); o.w = f2b(v.w);
    *(ushort4*)(xb + i) = o;
}

// ------------- transpose+convert W[k][n] -> Wt[n][k] (bf16, row-major BT) -------------
__global__ __launch_bounds__(1024) void transpose_w_kernel(const float* __restrict__ Wq,
                                                           const float* __restrict__ Wk,
                                                           const float* __restrict__ Wv,
                                                           unsigned short* __restrict__ Wt) {
    __shared__ float tile[32][33];
    const float* W = (blockIdx.z == 0) ? Wq : (blockIdx.z == 1) ? Wk : Wv;
    int n0 = blockIdx.x * 32, k0 = blockIdx.y * 32;
    int tx = threadIdx.x, ty = threadIdx.y;
    tile[ty][tx] = W[(k0 + ty) * 1024 + n0 + tx];
    __syncthreads();
    Wt[((long)blockIdx.z * 1024 + n0 + ty) * 1024 + k0 + tx] = f2b(tile[tx][ty]);
}

// ------------- occupancy-tuned BT-form bf16 MFMA GEMM -------------
// C[m][n] = sum_k A[m][k]*B[n][k].  128x64 block tile, BK=64, 4 waves,
// wave-tile 32x64 (1x2 of v_mfma_f32_32x32x16_bf16) -> only 32 AGPR acc,
// small VGPR footprint -> 5-6 waves/SIMD for latency cover (this-shape GEMMs
// were latency-bound at 3 waves/SIMD, pinned ~25% MfmaUtil across rounds 1-5).
// LDS rows = 64 bf16 (128 B), XOR-swizzled 16B chunks (phys = log ^ (row&7)).
// EPI 0: QKV epilogue (bias; Q scaled; Q,K row-major; V transposed store)
// EPI 1: bf16 row-major S (ldc 2048)
// EPI 2: fp32 row-major out (ldc 1024)
template <int EPI>
__global__ __launch_bounds__(256, 4) void gemm64(const unsigned short* __restrict__ A, int lda, long sA,
                                                 const unsigned short* __restrict__ Bm, int ldb, long sB,
                                                 void* __restrict__ Cv, long sC, int K,
                                                 const float* __restrict__ bq, const float* __restrict__ bk,
                                                 const float* __restrict__ bv,
                                                 unsigned short* __restrict__ Qb,
                                                 unsigned short* __restrict__ Kb,
                                                 unsigned short* __restrict__ Vt) {
    __shared__ unsigned short As[128 * 64];   // 16 KB
    __shared__ unsigned short Bs[64 * 64];    //  8 KB

    const int tid = threadIdx.x;
    const int wave = tid >> 6, lane = tid & 63;
    const int h = lane >> 5;
    const int l31 = lane & 31;
    const long bm = (long)blockIdx.y * 128;
    const long bn = (long)blockIdx.x * 64;

    const unsigned short* Ab = A + (long)blockIdx.z * sA;
    const unsigned short* Bb = Bm + (long)blockIdx.z * sB;

    f32x16 acc[2];
#pragma unroll
    for (int ni = 0; ni < 2; ++ni)
#pragma unroll
        for (int r = 0; r < 16; ++r) acc[ni][r] = 0.0f;

    // ---- staging: per thread, A rows {j*32 + wave*8 + (lane>>3)} j=0..3, B j=0..1
    const int srow_in = lane >> 3;                 // 0..7
    const int cswz = (lane & 7) ^ srow_in;         // swizzled 16B chunk 0..7
    const unsigned short* aptr[4];
    const unsigned short* bptr[2];
    int asloff[4], bsloff[2];
#pragma unroll
    for (int j = 0; j < 4; ++j) {
        const int row = j * 32 + wave * 8 + srow_in;
        aptr[j] = Ab + (bm + row) * (long)lda + cswz * 8;
        asloff[j] = (j * 32 + wave * 8) * 64;
    }
#pragma unroll
    for (int j = 0; j < 2; ++j) {
        const int row = j * 32 + wave * 8 + srow_in;
        bptr[j] = Bb + (bn + row) * (long)ldb + cswz * 8;
        bsloff[j] = (j * 32 + wave * 8) * 64;
    }

    // ---- fragment swizzled k-offsets: kstep s (k=s*16+h*8), chunk (2s+h)^(l31&7)
    int sw[4];
#pragma unroll
    for (int s = 0; s < 4; ++s)
        sw[s] = ((2 * s + h) ^ (l31 & 7)) * 8;
    const int arow = (wave * 32 + l31) * 64;

    for (int k0 = 0; k0 < K; k0 += 64) {
#pragma unroll
        for (int j = 0; j < 4; ++j)
            __builtin_amdgcn_global_load_lds((const __attribute__((address_space(1))) void*)(aptr[j] + k0),
                                             (__attribute__((address_space(3))) void*)&As[asloff[j]], 16, 0, 0);
#pragma unroll
        for (int j = 0; j < 2; ++j)
            __builtin_amdgcn_global_load_lds((const __attribute__((address_space(1))) void*)(bptr[j] + k0),
                                             (__attribute__((address_space(3))) void*)&Bs[bsloff[j]], 16, 0, 0);
        __syncthreads();

#pragma unroll
        for (int sp = 0; sp < 2; ++sp) {
            bf16x8 af[2], bfr[2][2];
#pragma unroll
            for (int s = 0; s < 2; ++s) {
                af[s] = *(const bf16x8*)&As[arow + sw[sp * 2 + s]];
#pragma unroll
                for (int ni = 0; ni < 2; ++ni)
                    bfr[s][ni] = *(const bf16x8*)&Bs[(ni * 32 + l31) * 64 + sw[sp * 2 + s]];
            }
#pragma unroll
            for (int s = 0; s < 2; ++s)
#pragma unroll
                for (int ni = 0; ni < 2; ++ni)
                    acc[ni] = __builtin_amdgcn_mfma_f32_32x32x16_bf16(af[s], bfr[s][ni], acc[ni], 0, 0, 0);
        }
        __syncthreads();
    }

    // ---- epilogue. 32x32 C/D layout: col = lane&31, row = (reg&3) + 8*(reg>>2) + 4*(lane>>5)
    const long rowB = bm + wave * 32 + h * 4;
#pragma unroll
    for (int ni = 0; ni < 2; ++ni) {
        const f32x16 a = acc[ni];
        const long col = bn + ni * 32 + l31;
        if constexpr (EPI == 0) {
            if (col < 1024) {
                const float bias = bq[col];
#pragma unroll
                for (int g = 0; g < 4; ++g)
#pragma unroll
                    for (int r = 0; r < 4; ++r)
                        Qb[(rowB + g * 8 + r) * 1024 + col] = f2b((a[g * 4 + r] + bias) * 0.03125f);
            } else if (col < 2048) {
                const float bias = bk[col - 1024];
#pragma unroll
                for (int g = 0; g < 4; ++g)
#pragma unroll
                    for (int r = 0; r < 4; ++r)
                        Kb[(rowB + g * 8 + r) * 1024 + (col - 1024)] = f2b(a[g * 4 + r] + bias);
            } else {
                const float bias = bv[col - 2048];
#pragma unroll
                for (int g = 0; g < 4; ++g) {
                    const long row0 = rowB + g * 8;
                    const long batch = row0 >> 11;
                    const int n = (int)(row0 & 2047);     // multiple of 4
                    ushort4 o;
                    o.x = f2b(a[g * 4 + 0] + bias);
                    o.y = f2b(a[g * 4 + 1] + bias);
                    o.z = f2b(a[g * 4 + 2] + bias);
                    o.w = f2b(a[g * 4 + 3] + bias);
                    *(ushort4*)&Vt[(batch * 1024 + (col - 2048)) * 2048 + n] = o;
                }
            }
        } else if constexpr (EPI == 1) {
            unsigned short* S = (unsigned short*)Cv + (long)blockIdx.z * sC;
#pragma unroll
            for (int g = 0; g < 4; ++g)
#pragma unroll
                for (int r = 0; r < 4; ++r)
                    S[(rowB + g * 8 + r) * 2048 + col] = f2b(a[g * 4 + r]);
        } else {
            float* O = (float*)Cv + (long)blockIdx.z * sC;
#pragma unroll
            for (int g = 0; g < 4; ++g)
#pragma unroll
                for (int r = 0; r < 4; ++r)
                    O[(rowB + g * 8 + r) * 1024 + col] = a[g * 4 + r];
        }
    }
}

// ---------------- row softmax over 2048 bf16, in place ----------------
__global__ __launch_bounds__(256) void softmax_kernel(unsigned short* __restrict__ S) {
    const long row = blockIdx.x;
    unsigned short* p = S + row * 2048;
    const int tid = threadIdx.x;
    const int wave = tid >> 6, lane = tid & 63;

    ushort4 u0 = *(const ushort4*)&p[tid * 8];
    ushort4 u1 = *(const ushort4*)&p[tid * 8 + 4];
    float v[8];
    v[0] = b2f(u0.x); v[1] = b2f(u0.y); v[2] = b2f(u0.z); v[3] = b2f(u0.w);
    v[4] = b2f(u1.x); v[5] = b2f(u1.y); v[6] = b2f(u1.z); v[7] = b2f(u1.w);

    float m = v[0];
#pragma unroll
    for (int j = 1; j < 8; ++j) m = fmaxf(m, v[j]);
#pragma unroll
    for (int off = 32; off; off >>= 1) m = fmaxf(m, __shfl_xor(m, off, 64));
    __shared__ float redm[4];
    __shared__ float reds[4];
    if (lane == 0) redm[wave] = m;
    __syncthreads();
    m = fmaxf(fmaxf(redm[0], redm[1]), fmaxf(redm[2], redm[3]));

    float s = 0.0f;
#pragma unroll
    for (int j = 0; j < 8; ++j) { v[j] = __expf(v[j] - m); s += v[j]; }
#pragma unroll
    for (int off = 32; off; off >>= 1) s += __shfl_xor(s, off, 64);
    if (lane == 0) reds[wave] = s;
    __syncthreads();
    s = reds[0] + reds[1] + reds[2] + reds[3];
    const float inv = 1.0f / s;

    u0.x = f2b(v[0] * inv); u0.y = f2b(v[1] * inv); u0.z = f2b(v[2] * inv); u0.w = f2b(v[3] * inv);
    u1.x = f2b(v[4] * inv); u1.y = f2b(v[5] * inv); u1.z = f2b(v[6] * inv); u1.w = f2b(v[7] * inv);
    *(ushort4*)&p[tid * 8] = u0;
    *(ushort4*)&p[tid * 8 + 4] = u1;
}

extern "C" void kernel_launch(void* const* d_in, const int* in_sizes, int n_in,
                              void* d_out, int out_size, void* d_ws, size_t ws_size,
                              hipStream_t stream) {
    const float* x  = (const float*)d_in[0];
    const float* Wq = (const float*)d_in[1];
    const float* Wk = (const float*)d_in[2];
    const float* Wv = (const float*)d_in[3];
    const float* bq = (const float*)d_in[4];
    const float* bk = (const float*)d_in[5];
    const float* bv = (const float*)d_in[6];
    float* out = (float*)d_out;

    char* ws = (char*)d_ws;
    unsigned short* xb = (unsigned short*)ws; ws += 8192L * 1024 * 2;   // row-major
    unsigned short* Wt = (unsigned short*)ws; ws += 3072L * 1024 * 2;   // BT row-major
    unsigned short* Qb = (unsigned short*)ws; ws += 8192L * 1024 * 2;
    unsigned short* Kb = (unsigned short*)ws; ws += 8192L * 1024 * 2;
    unsigned short* Vt = (unsigned short*)ws; ws += 4L * 1024 * 2048 * 2;
    unsigned short* S  = (unsigned short*)ws; ws += 4L * 2048 * 2048 * 2;

    convert_x_kernel<<<8192, 256, 0, stream>>>(x, xb);
    transpose_w_kernel<<<dim3(32, 32, 3), dim3(32, 32), 0, stream>>>(Wq, Wk, Wv, Wt);
    // QKV projection: [8192,3072] = xb @ Wt^T (+bias; Q scaled; V stored transposed)
    gemm64<0><<<dim3(48, 64, 1), 256, 0, stream>>>(xb, 1024, 0, Wt, 1024, 0,
                                                   nullptr, 0, 1024, bq, bk, bv, Qb, Kb, Vt);
    // S[b] = Q[b] @ K[b]^T (Q pre-scaled by 1/32)
    gemm64<1><<<dim3(32, 16, 4), 256, 0, stream>>>(Qb, 1024, 2048L * 1024, Kb, 1024, 2048L * 1024,
                                                   S, 2048L * 2048, 1024,
                                                   nullptr, nullptr, nullptr, nullptr, nullptr, nullptr);
    softmax_kernel<<<8192, 256, 0, stream>>>(S);
    // out[b] = P[b] @ Vt[b]^T (fp32 out)
    gemm64<2><<<dim3(16, 16, 4), 256, 0, stream>>>(S, 2048, 2048L * 2048, Vt, 2048, 2048L * 1024,
                                                   out, 2048L * 1024, 2048,
                                                   nullptr, nullptr, nullptr, nullptr, nullptr, nullptr);
}